// Round 1
// baseline (440.363 us; speedup 1.0000x reference)
//
#include <hip/hip_runtime.h>
#include <hip/hip_bf16.h>
#include <math.h>

// Problem constants
#define NB 4
#define NSQ 2048
#define NSKV 2048
#define ND 1024

typedef __attribute__((ext_vector_type(8))) __bf16 bf16x8;
typedef __attribute__((ext_vector_type(4))) float f32x4;

__device__ __forceinline__ unsigned short f2bf(float x) {
  __hip_bfloat16 h = __float2bfloat16(x);
  return __builtin_bit_cast(unsigned short, h);
}

__device__ __forceinline__ void gload_lds16(const void* g, void* l) {
  __builtin_amdgcn_global_load_lds((const __attribute__((address_space(1))) void*)g,
                                   (__attribute__((address_space(3))) void*)l,
                                   16, 0, 0);
}

// ---------------- fp32 -> bf16 conversion (vectorized) ----------------
__global__ __launch_bounds__(256) void cvt_bf16(const float* __restrict__ s,
                                                unsigned short* __restrict__ d,
                                                int n4) {
  int i = blockIdx.x * blockDim.x + threadIdx.x;
  if (i >= n4) return;
  float4 v = ((const float4*)s)[i];
  ushort4 o;
  o.x = f2bf(v.x); o.y = f2bf(v.y); o.z = f2bf(v.z); o.w = f2bf(v.w);
  ((ushort4*)d)[i] = o;
}

// ---------------- NT GEMM: C[m][n] = sum_k A[m][k]*B[n][k] ----------------
// 128x128 tile, BK=32, 4 waves (2x2 of 64x64), mfma_f32_16x16x32_bf16.
// BIAS_MODE: 0 none, 1 bias[col], 2 bias[row]. OUT_BF16: output dtype.
template <int BIAS_MODE, int OUT_BF16>
__global__ __launch_bounds__(256)
void gemm_nt(const unsigned short* __restrict__ A,
             const unsigned short* __restrict__ B,
             const float* __restrict__ bias, float scale,
             void* __restrict__ Cout,
             int K, int lda, int ldb, int ldc,
             long strideA, long strideB, long strideC) {
  __shared__ __align__(16) unsigned short sA[128 * 32];
  __shared__ __align__(16) unsigned short sB[128 * 32];
  const int tid = threadIdx.x;
  const int wave = tid >> 6;
  const int lane = tid & 63;
  const long brow = (long)blockIdx.y * 128;
  const long bcol = (long)blockIdx.x * 128;
  const unsigned short* Ab = A + (long)blockIdx.z * strideA;
  const unsigned short* Bb = B + (long)blockIdx.z * strideB;

  const int wr = wave >> 1;  // wave row quadrant (0..1)
  const int wc = wave & 1;   // wave col quadrant (0..1)

  f32x4 acc[4][4];
#pragma unroll
  for (int m = 0; m < 4; ++m)
#pragma unroll
    for (int n = 0; n < 4; ++n) {
      f32x4 z = {0.f, 0.f, 0.f, 0.f};
      acc[m][n] = z;
    }

  // staging: tile is 128 rows x 32 cols bf16 = 512 chunks of 16B (8 elems)
  // chunk c -> row c>>2, colchunk c&3. thread handles chunks (wave*64+lane) and +256.
  const int c0 = wave * 64 + lane;
  const int c1 = c0 + 256;
  const unsigned short* agp0 = Ab + (brow + (c0 >> 2)) * (long)lda + (c0 & 3) * 8;
  const unsigned short* agp1 = Ab + (brow + (c1 >> 2)) * (long)lda + (c1 & 3) * 8;
  const unsigned short* bgp0 = Bb + (bcol + (c0 >> 2)) * (long)ldb + (c0 & 3) * 8;
  const unsigned short* bgp1 = Bb + (bcol + (c1 >> 2)) * (long)ldb + (c1 & 3) * 8;
  // LDS dest: wave-uniform base; HW adds lane*16B
  unsigned short* la0 = sA + wave * 512;
  unsigned short* la1 = sA + wave * 512 + 2048;
  unsigned short* lb0 = sB + wave * 512;
  unsigned short* lb1 = sB + wave * 512 + 2048;

  const int fr = lane & 15;
  const int ko = (lane >> 4) * 8;
  const int nk = K >> 5;

  for (int kt = 0; kt < nk; ++kt) {
    gload_lds16(agp0, la0);
    gload_lds16(agp1, la1);
    gload_lds16(bgp0, lb0);
    gload_lds16(bgp1, lb1);
    agp0 += 32; agp1 += 32; bgp0 += 32; bgp1 += 32;
    __syncthreads();  // drains vmcnt(0): staged data visible

    bf16x8 af[4], bfr[4];
#pragma unroll
    for (int m = 0; m < 4; ++m)
      af[m] = *(const bf16x8*)(sA + (wr * 64 + m * 16 + fr) * 32 + ko);
#pragma unroll
    for (int n = 0; n < 4; ++n)
      bfr[n] = *(const bf16x8*)(sB + (wc * 64 + n * 16 + fr) * 32 + ko);
#pragma unroll
    for (int m = 0; m < 4; ++m)
#pragma unroll
      for (int n = 0; n < 4; ++n)
        acc[m][n] = __builtin_amdgcn_mfma_f32_16x16x32_bf16(af[m], bfr[n], acc[m][n], 0, 0, 0);
    __syncthreads();  // all reads done before next stage overwrites
  }

  // epilogue: C/D layout col=lane&15, row=(lane>>4)*4+reg
  const int fq = lane >> 4;
#pragma unroll
  for (int m = 0; m < 4; ++m) {
#pragma unroll
    for (int n = 0; n < 4; ++n) {
#pragma unroll
      for (int r = 0; r < 4; ++r) {
        long row = brow + wr * 64 + m * 16 + fq * 4 + r;
        long col = bcol + wc * 64 + n * 16 + fr;
        float v = acc[m][n][r] * scale;
        if (BIAS_MODE == 1) v += bias[col];
        if (BIAS_MODE == 2) v += bias[row];
        long idx = (long)blockIdx.z * strideC + row * (long)ldc + col;
        if (OUT_BF16)
          ((unsigned short*)Cout)[idx] = f2bf(v);
        else
          ((float*)Cout)[idx] = v;
      }
    }
  }
}

// ---------------- masked softmax over rows of 2048, fp32 -> bf16 ----------------
__global__ __launch_bounds__(256)
void softmax_mask(const float* __restrict__ S, const int* __restrict__ Mk,
                  unsigned short* __restrict__ P) {
  const long row = blockIdx.x;
  const float* s = S + row * NSKV;
  const int* mk = Mk + row * NSKV;
  unsigned short* p = P + row * NSKV;
  const int t = threadIdx.x;
  const int lane = t & 63;
  const int wave = t >> 6;

  float4 v0 = ((const float4*)s)[t * 2];
  float4 v1 = ((const float4*)s)[t * 2 + 1];
  int4 m0 = ((const int4*)mk)[t * 2];
  int4 m1 = ((const int4*)mk)[t * 2 + 1];
  float x[8];
  x[0] = m0.x ? v0.x : -1e10f;
  x[1] = m0.y ? v0.y : -1e10f;
  x[2] = m0.z ? v0.z : -1e10f;
  x[3] = m0.w ? v0.w : -1e10f;
  x[4] = m1.x ? v1.x : -1e10f;
  x[5] = m1.y ? v1.y : -1e10f;
  x[6] = m1.z ? v1.z : -1e10f;
  x[7] = m1.w ? v1.w : -1e10f;

  float mx = x[0];
#pragma unroll
  for (int j = 1; j < 8; ++j) mx = fmaxf(mx, x[j]);
#pragma unroll
  for (int o = 32; o > 0; o >>= 1) mx = fmaxf(mx, __shfl_xor(mx, o, 64));
  __shared__ float red[8];
  if (lane == 0) red[wave] = mx;
  __syncthreads();
  mx = fmaxf(fmaxf(red[0], red[1]), fmaxf(red[2], red[3]));

  float e[8];
  float sum = 0.f;
#pragma unroll
  for (int j = 0; j < 8; ++j) {
    e[j] = __expf(x[j] - mx);
    sum += e[j];
  }
#pragma unroll
  for (int o = 32; o > 0; o >>= 1) sum += __shfl_xor(sum, o, 64);
  if (lane == 0) red[4 + wave] = sum;
  __syncthreads();
  sum = red[4] + red[5] + red[6] + red[7];
  float inv = 1.f / sum;

  ushort4 o0, o1;
  o0.x = f2bf(e[0] * inv); o0.y = f2bf(e[1] * inv);
  o0.z = f2bf(e[2] * inv); o0.w = f2bf(e[3] * inv);
  o1.x = f2bf(e[4] * inv); o1.y = f2bf(e[5] * inv);
  o1.z = f2bf(e[6] * inv); o1.w = f2bf(e[7] * inv);
  ((ushort4*)p)[t * 2] = o0;
  ((ushort4*)p)[t * 2 + 1] = o1;
}

// ---------------- launcher ----------------
extern "C" void kernel_launch(void* const* d_in, const int* in_sizes, int n_in,
                              void* d_out, int out_size, void* d_ws, size_t ws_size,
                              hipStream_t stream) {
  const float* input  = (const float*)d_in[0];
  const float* memory = (const float*)d_in[1];
  const int*   mask   = (const int*)d_in[2];
  const float* Wq = (const float*)d_in[3];
  const float* bq = (const float*)d_in[4];
  const float* Wk = (const float*)d_in[5];
  const float* bk = (const float*)d_in[6];
  const float* Wv = (const float*)d_in[7];
  const float* bv = (const float*)d_in[8];
  const float* Wo = (const float*)d_in[9];
  const float* bo = (const float*)d_in[10];
  float* out = (float*)d_out;

  // workspace layout (ushort elements)
  unsigned short* wqb  = (unsigned short*)d_ws;
  unsigned short* wkb  = wqb + (1 << 20);
  unsigned short* wvb  = wkb + (1 << 20);
  unsigned short* wob  = wvb + (1 << 20);
  unsigned short* inb  = wob + (1 << 20);   // 8M elems
  unsigned short* memb = inb + (8 << 20);
  unsigned short* qb   = memb + (8 << 20);
  unsigned short* kb   = qb + (8 << 20);
  unsigned short* vtb  = kb + (8 << 20);    // Vt_all: [1024][8192] (d-major)
  unsigned short* ctxb = vtb + (8 << 20);
  float* scoresf = (float*)(ctxb + (8 << 20));  // 16M floats
  unsigned short* pb = inb;  // P overlays inb+memb (16M ushorts), dead by then

  // conversions
  cvt_bf16<<<dim3(8192), 256, 0, stream>>>(input, inb, 2097152);
  cvt_bf16<<<dim3(8192), 256, 0, stream>>>(memory, memb, 2097152);
  cvt_bf16<<<dim3(1024), 256, 0, stream>>>(Wq, wqb, 262144);
  cvt_bf16<<<dim3(1024), 256, 0, stream>>>(Wk, wkb, 262144);
  cvt_bf16<<<dim3(1024), 256, 0, stream>>>(Wv, wvb, 262144);
  cvt_bf16<<<dim3(1024), 256, 0, stream>>>(Wo, wob, 262144);

  // Q = input @ Wq^T + bq  -> [8192,1024] bf16
  gemm_nt<1, 1><<<dim3(8, 64, 1), 256, 0, stream>>>(
      inb, wqb, bq, 1.f, qb, ND, ND, ND, ND, 0, 0, 0);
  // K = memory @ Wk^T + bk -> [8192,1024] bf16
  gemm_nt<1, 1><<<dim3(8, 64, 1), 256, 0, stream>>>(
      memb, wkb, bk, 1.f, kb, ND, ND, ND, ND, 0, 0, 0);
  // Vt = Wv @ memory^T + bv(row) -> [1024,8192] bf16 (Vt[d][b*2048+kv] = V[b][kv][d])
  gemm_nt<2, 1><<<dim3(64, 8, 1), 256, 0, stream>>>(
      wvb, memb, bv, 1.f, vtb, ND, ND, ND, 8192, 0, 0, 0);
  // scores = (Q K^T) * 1/32 -> fp32, batched z=4
  gemm_nt<0, 0><<<dim3(16, 16, 4), 256, 0, stream>>>(
      qb, kb, nullptr, 0.03125f, scoresf, ND, ND, ND, NSKV,
      (long)NSQ * ND, (long)NSKV * ND, (long)NSQ * NSKV);
  // masked softmax -> P bf16
  softmax_mask<<<dim3(NB * NSQ), 256, 0, stream>>>(scoresf, mask, pb);
  // ctx = P @ V  (NT vs Vt) -> [b][2048][1024] bf16
  gemm_nt<0, 1><<<dim3(8, 16, 4), 256, 0, stream>>>(
      pb, vtb, nullptr, 1.f, ctxb, NSKV, NSKV, 8192, ND,
      (long)NSQ * NSKV, (long)NSKV, (long)NSQ * ND);
  // out = ctx @ Wo^T + bo -> fp32
  gemm_nt<1, 0><<<dim3(8, 64, 1), 256, 0, stream>>>(
      ctxb, wob, bo, 1.f, out, ND, ND, ND, ND, 0, 0, 0);
}

// Round 5
// 397.088 us; speedup vs baseline: 1.1090x; 1.1090x over previous
//
#include <hip/hip_runtime.h>
#include <hip/hip_bf16.h>
#include <math.h>

// Problem constants
#define NB 4
#define NSQ 2048
#define NSKV 2048
#define ND 1024

typedef __attribute__((ext_vector_type(8))) __bf16 bf16x8;
typedef __attribute__((ext_vector_type(4))) float f32x4;

#define WAITV(N) asm volatile("s_waitcnt vmcnt(" #N ")" ::: "memory")
#define WAITL0() asm volatile("s_waitcnt lgkmcnt(0)" ::: "memory")
#define BAR() __builtin_amdgcn_s_barrier()

__device__ __forceinline__ unsigned short f2bf(float x) {
  __hip_bfloat16 h = __float2bfloat16(x);
  return __builtin_bit_cast(unsigned short, h);
}

__device__ __forceinline__ void gload_lds16(const void* g, void* l) {
  __builtin_amdgcn_global_load_lds((const __attribute__((address_space(1))) void*)g,
                                   (__attribute__((address_space(3))) void*)l,
                                   16, 0, 0);
}

// ---------------- fp32 -> bf16 conversion (vectorized) ----------------
__global__ __launch_bounds__(256) void cvt_bf16(const float* __restrict__ s,
                                                unsigned short* __restrict__ d,
                                                int n4) {
  int i = blockIdx.x * blockDim.x + threadIdx.x;
  if (i >= n4) return;
  float4 v = ((const float4*)s)[i];
  ushort4 o;
  o.x = f2bf(v.x); o.y = f2bf(v.y); o.z = f2bf(v.z); o.w = f2bf(v.w);
  ((ushort4*)d)[i] = o;
}

__global__ __launch_bounds__(256) void concat_bias(const float* __restrict__ a,
                                                   const float* __restrict__ b,
                                                   float* __restrict__ d) {
  int i = blockIdx.x * 256 + threadIdx.x;
  if (i < 1024) d[i] = a[i];
  else if (i < 2048) d[i] = b[i - 1024];
}

// ---------------- 256x256 8-phase NT GEMM ----------------
// C[m][n] = scale * sum_k A[m][k]*B[n][k] (+bias)
// BM=BN=256, BK=64, 512 threads = 8 waves (2M x 4N, interleaved sub-tiles).
// LDS: A[2buf][2half][128][64]bf16 (64KB) + B same (64KB) = 128KB dynamic.
// Rotate swizzle: chunk slot = row*8 + ((kc+row)&7), via pre-swizzled global src.
// Requires M%256==0, N%256==0, K%128==0, K>=256.
template <int BIAS_MODE, int OUT_BF16>   // BIAS: 0 none, 1 bias[col], 2 bias[row]
__global__ __launch_bounds__(512)
void gemm256(const unsigned short* __restrict__ A,
             const unsigned short* __restrict__ B,
             const float* __restrict__ bias, int biasStride, float scale,
             void* __restrict__ Cout,
             int K, int lda, int ldb, int ldc,
             long strideA, long strideB, long strideC) {
  extern __shared__ __align__(16) char smem[];
  char* ldsA = smem;            // [2][2][128][64] bf16
  char* ldsB = smem + 65536;

  const int tid = threadIdx.x;
  const int w  = tid >> 6;
  const int l  = tid & 63;
  const int wm = w >> 2;        // 0..1
  const int wn = w & 3;         // 0..3
  const int fr = l & 15;
  const int fq = l >> 4;

  const long brow = (long)blockIdx.y * 256;
  const long bcol = (long)blockIdx.x * 256;
  const unsigned short* Ab = A + (long)blockIdx.z * strideA;
  const unsigned short* Bb = B + (long)blockIdx.z * strideB;
  const float* biasb = (BIAS_MODE ? bias + (long)blockIdx.z * (long)biasStride : nullptr);

  const int NT = K >> 6;

  // staging lane constants: c = r*512 + w*64 + l, row=c>>3 in [0,128), j=c&7
  int srow[2], skc[2];
#pragma unroll
  for (int r = 0; r < 2; ++r) {
    int c = r * 512 + w * 64 + l;
    srow[r] = c >> 3;
    skc[r] = ((c & 7) - srow[r]) & 7;
  }
  const int sldsoff0 = (w * 64) * 16;          // wave-uniform LDS offsets
  const int sldsoff1 = (512 + w * 64) * 16;

  auto STAGE = [&](int isB, int T, int h) {
    const unsigned short* Gb = isB ? Bb : Ab;
    const int ld = isB ? ldb : lda;
    const long rb = (isB ? bcol : brow) + h * 128;
    char* seg = (isB ? ldsB : ldsA) + (T & 1) * 32768 + h * 16384;
    gload_lds16(Gb + (rb + srow[0]) * (long)ld + T * 64 + skc[0] * 8, seg + sldsoff0);
    gload_lds16(Gb + (rb + srow[1]) * (long)ld + T * 64 + skc[1] * 8, seg + sldsoff1);
  };

  auto LDFRAG = [&](const char* seg, int row, int kc) -> bf16x8 {
    return *(const bf16x8*)(seg + row * 128 + (((kc + row) & 7) << 4));
  };

  f32x4 acc[8][4];
#pragma unroll
  for (int mi = 0; mi < 8; ++mi)
#pragma unroll
    for (int ni = 0; ni < 4; ++ni) {
      f32x4 z = {0.f, 0.f, 0.f, 0.f};
      acc[mi][ni] = z;
    }

  bf16x8 af[4][2], bfr[2][2];

  // ---- prologue: t0 {Ah0,Bh0,Bh1,Ah1}; vmcnt(4); t1 {Ah0,Bh1,Ah1}; vmcnt(6)
  STAGE(0, 0, 0); STAGE(1, 0, 0); STAGE(1, 0, 1); STAGE(0, 0, 1);
  WAITV(4);
  STAGE(0, 1, 0); STAGE(1, 1, 1); STAGE(0, 1, 1);
  WAITV(6);
  BAR();

  for (int t = 0; t < NT; ++t) {
    const int cb = t & 1;
    const char* a0 = ldsA + cb * 32768;
    const char* a1 = a0 + 16384;
    const char* b0 = ldsB + cb * 32768;
    const char* b1 = b0 + 16384;

    // ---- P1: read A-mlo + B-nlo ; stage (t+1).Bh0 ; mfma mlo x nlo
#pragma unroll
    for (int mi = 0; mi < 4; ++mi)
#pragma unroll
      for (int ks = 0; ks < 2; ++ks)
        af[mi][ks] = LDFRAG(a0, wm * 64 + mi * 16 + fr, ks * 4 + fq);
#pragma unroll
    for (int ni = 0; ni < 2; ++ni)
#pragma unroll
      for (int ks = 0; ks < 2; ++ks)
        bfr[ni][ks] = LDFRAG(b0, wn * 32 + ni * 16 + fr, ks * 4 + fq);
    if (t + 1 < NT) STAGE(1, t + 1, 0);
    BAR(); WAITL0();
    __builtin_amdgcn_s_setprio(1);
#pragma unroll
    for (int ks = 0; ks < 2; ++ks)
#pragma unroll
      for (int mi = 0; mi < 4; ++mi)
#pragma unroll
        for (int ni = 0; ni < 2; ++ni)
          acc[mi][ni] = __builtin_amdgcn_mfma_f32_16x16x32_bf16(af[mi][ks], bfr[ni][ks], acc[mi][ni], 0, 0, 0);
    __builtin_amdgcn_s_setprio(0);
    BAR();

    // ---- P2: read B-nhi ; stage (t+2).Ah0 ; mfma mlo x nhi
#pragma unroll
    for (int ni = 0; ni < 2; ++ni)
#pragma unroll
      for (int ks = 0; ks < 2; ++ks)
        bfr[ni][ks] = LDFRAG(b1, wn * 32 + ni * 16 + fr, ks * 4 + fq);
    if (t + 2 < NT) STAGE(0, t + 2, 0);
    BAR(); WAITL0();
    __builtin_amdgcn_s_setprio(1);
#pragma unroll
    for (int ks = 0; ks < 2; ++ks)
#pragma unroll
      for (int mi = 0; mi < 4; ++mi)
#pragma unroll
        for (int ni = 0; ni < 2; ++ni)
          acc[mi][2 + ni] = __builtin_amdgcn_mfma_f32_16x16x32_bf16(af[mi][ks], bfr[ni][ks], acc[mi][2 + ni], 0, 0, 0);
    __builtin_amdgcn_s_setprio(0);
    BAR();

    // ---- P3: read A-mhi ; stage (t+2).Bh1 ; mfma mhi x nhi
#pragma unroll
    for (int mi = 0; mi < 4; ++mi)
#pragma unroll
      for (int ks = 0; ks < 2; ++ks)
        af[mi][ks] = LDFRAG(a1, wm * 64 + mi * 16 + fr, ks * 4 + fq);
    if (t + 2 < NT) STAGE(1, t + 2, 1);
    BAR(); WAITL0();
    __builtin_amdgcn_s_setprio(1);
#pragma unroll
    for (int ks = 0; ks < 2; ++ks)
#pragma unroll
      for (int mi = 0; mi < 4; ++mi)
#pragma unroll
        for (int ni = 0; ni < 2; ++ni)
          acc[4 + mi][2 + ni] = __builtin_amdgcn_mfma_f32_16x16x32_bf16(af[mi][ks], bfr[ni][ks], acc[4 + mi][2 + ni], 0, 0, 0);
    __builtin_amdgcn_s_setprio(0);
    BAR();

    // ---- P4: re-read B-nlo ; stage (t+2).Ah1 ; mfma mhi x nlo ; group-end vmcnt
#pragma unroll
    for (int ni = 0; ni < 2; ++ni)
#pragma unroll
      for (int ks = 0; ks < 2; ++ks)
        bfr[ni][ks] = LDFRAG(b0, wn * 32 + ni * 16 + fr, ks * 4 + fq);
    if (t + 2 < NT) STAGE(0, t + 2, 1);
    BAR(); WAITL0();
    __builtin_amdgcn_s_setprio(1);
#pragma unroll
    for (int ks = 0; ks < 2; ++ks)
#pragma unroll
      for (int mi = 0; mi < 4; ++mi)
#pragma unroll
        for (int ni = 0; ni < 2; ++ni)
          acc[4 + mi][ni] = __builtin_amdgcn_mfma_f32_16x16x32_bf16(af[mi][ks], bfr[ni][ks], acc[4 + mi][ni], 0, 0, 0);
    __builtin_amdgcn_s_setprio(0);
    if (t < NT - 2) { WAITV(6); } else if (t == NT - 2) { WAITV(0); }
    BAR();
  }

  // ---- epilogue: C/D layout col=lane&15, row=(lane>>4)*4+reg
#pragma unroll
  for (int mi = 0; mi < 8; ++mi) {
#pragma unroll
    for (int ni = 0; ni < 4; ++ni) {
#pragma unroll
      for (int r = 0; r < 4; ++r) {
        long row = brow + (mi >> 2) * 128 + wm * 64 + (mi & 3) * 16 + fq * 4 + r;
        long col = bcol + (ni >> 1) * 128 + wn * 32 + (ni & 1) * 16 + fr;
        float v = acc[mi][ni][r] * scale;
        if (BIAS_MODE == 1) v += biasb[col];
        if (BIAS_MODE == 2) v += biasb[row];
        long idx = (long)blockIdx.z * strideC + row * (long)ldc + col;
        if (OUT_BF16)
          ((unsigned short*)Cout)[idx] = f2bf(v);
        else
          ((float*)Cout)[idx] = v;
      }
    }
  }
}

// ---------------- masked softmax over rows of 2048, fp32 -> bf16 ----------------
__global__ __launch_bounds__(256)
void softmax_mask(const float* __restrict__ S, const int* __restrict__ Mk,
                  unsigned short* __restrict__ P) {
  const long row = blockIdx.x;
  const float* s = S + row * NSKV;
  const int* mk = Mk + row * NSKV;
  unsigned short* p = P + row * NSKV;
  const int t = threadIdx.x;
  const int lane = t & 63;
  const int wave = t >> 6;

  float4 v0 = ((const float4*)s)[t * 2];
  float4 v1 = ((const float4*)s)[t * 2 + 1];
  int4 m0 = ((const int4*)mk)[t * 2];
  int4 m1 = ((const int4*)mk)[t * 2 + 1];
  float x[8];
  x[0] = m0.x ? v0.x : -1e10f;
  x[1] = m0.y ? v0.y : -1e10f;
  x[2] = m0.z ? v0.z : -1e10f;
  x[3] = m0.w ? v0.w : -1e10f;
  x[4] = m1.x ? v1.x : -1e10f;
  x[5] = m1.y ? v1.y : -1e10f;
  x[6] = m1.z ? v1.z : -1e10f;
  x[7] = m1.w ? v1.w : -1e10f;

  float mx = x[0];
#pragma unroll
  for (int j = 1; j < 8; ++j) mx = fmaxf(mx, x[j]);
#pragma unroll
  for (int o = 32; o > 0; o >>= 1) mx = fmaxf(mx, __shfl_xor(mx, o, 64));
  __shared__ float red[8];
  if (lane == 0) red[wave] = mx;
  __syncthreads();
  mx = fmaxf(fmaxf(red[0], red[1]), fmaxf(red[2], red[3]));

  float e[8];
  float sum = 0.f;
#pragma unroll
  for (int j = 0; j < 8; ++j) {
    e[j] = __expf(x[j] - mx);
    sum += e[j];
  }
#pragma unroll
  for (int o = 32; o > 0; o >>= 1) sum += __shfl_xor(sum, o, 64);
  if (lane == 0) red[4 + wave] = sum;
  __syncthreads();
  sum = red[4] + red[5] + red[6] + red[7];
  float inv = 1.f / sum;

  ushort4 o0, o1;
  o0.x = f2bf(e[0] * inv); o0.y = f2bf(e[1] * inv);
  o0.z = f2bf(e[2] * inv); o0.w = f2bf(e[3] * inv);
  o1.x = f2bf(e[4] * inv); o1.y = f2bf(e[5] * inv);
  o1.z = f2bf(e[6] * inv); o1.w = f2bf(e[7] * inv);
  ((ushort4*)p)[t * 2] = o0;
  ((ushort4*)p)[t * 2 + 1] = o1;
}

// ---------------- launcher ----------------
extern "C" void kernel_launch(void* const* d_in, const int* in_sizes, int n_in,
                              void* d_out, int out_size, void* d_ws, size_t ws_size,
                              hipStream_t stream) {
  const float* input  = (const float*)d_in[0];
  const float* memory = (const float*)d_in[1];
  const int*   mask   = (const int*)d_in[2];
  const float* Wq = (const float*)d_in[3];
  const float* bq = (const float*)d_in[4];
  const float* Wk = (const float*)d_in[5];
  const float* bk = (const float*)d_in[6];
  const float* Wv = (const float*)d_in[7];
  const float* bv = (const float*)d_in[8];
  const float* Wo = (const float*)d_in[9];
  const float* bo = (const float*)d_in[10];
  float* out = (float*)d_out;

  // workspace layout (ushort elements)
  unsigned short* wqb  = (unsigned short*)d_ws;
  unsigned short* wkb  = wqb + (1 << 20);
  unsigned short* wvb  = wkb + (1 << 20);
  unsigned short* wob  = wvb + (1 << 20);
  unsigned short* inb  = wob + (1 << 20);   // 8M elems
  unsigned short* memb = inb + (8 << 20);
  unsigned short* qb   = memb + (8 << 20);
  unsigned short* kb   = qb + (8 << 20);
  unsigned short* vtb  = kb + (8 << 20);    // Vt_all: [1024][8192]
  unsigned short* ctxb = vtb + (8 << 20);
  float* scoresf = (float*)(ctxb + (8 << 20));   // 16M floats
  float* biasqk  = scoresf + (16 << 20);         // 2048 floats
  unsigned short* pb = inb;  // P overlays inb+memb (16M ushorts), dead by then

  const int SMEM = 131072;
  hipFuncSetAttribute((const void*)&gemm256<1, 1>, hipFuncAttributeMaxDynamicSharedMemorySize, SMEM);
  hipFuncSetAttribute((const void*)&gemm256<2, 1>, hipFuncAttributeMaxDynamicSharedMemorySize, SMEM);
  hipFuncSetAttribute((const void*)&gemm256<0, 0>, hipFuncAttributeMaxDynamicSharedMemorySize, SMEM);
  hipFuncSetAttribute((const void*)&gemm256<0, 1>, hipFuncAttributeMaxDynamicSharedMemorySize, SMEM);
  hipFuncSetAttribute((const void*)&gemm256<1, 0>, hipFuncAttributeMaxDynamicSharedMemorySize, SMEM);

  // conversions + bias concat
  cvt_bf16<<<dim3(8192), 256, 0, stream>>>(input, inb, 2097152);
  cvt_bf16<<<dim3(8192), 256, 0, stream>>>(memory, memb, 2097152);
  cvt_bf16<<<dim3(1024), 256, 0, stream>>>(Wq, wqb, 262144);
  cvt_bf16<<<dim3(1024), 256, 0, stream>>>(Wk, wkb, 262144);
  cvt_bf16<<<dim3(1024), 256, 0, stream>>>(Wv, wvb, 262144);
  cvt_bf16<<<dim3(1024), 256, 0, stream>>>(Wo, wob, 262144);
  concat_bias<<<dim3(8), 256, 0, stream>>>(bq, bk, biasqk);

  // fused Q/K projection: z=0 -> Q from input/Wq, z=1 -> K from memory/Wk
  gemm256<1, 1><<<dim3(4, 32, 2), 512, SMEM, stream>>>(
      inb, wqb, biasqk, 1024, 1.f, qb, ND, ND, ND, ND,
      (long)(8 << 20), (long)(1 << 20), (long)(8 << 20));
  // Vt = Wv @ memory^T + bv(row): [1024][8192]
  gemm256<2, 1><<<dim3(32, 4, 1), 512, SMEM, stream>>>(
      wvb, memb, bv, 0, 1.f, vtb, ND, ND, ND, 8192, 0, 0, 0);
  // scores = (Q K^T) * 1/32 -> fp32, z=4
  gemm256<0, 0><<<dim3(8, 8, 4), 512, SMEM, stream>>>(
      qb, kb, nullptr, 0, 0.03125f, scoresf, ND, ND, ND, NSKV,
      (long)NSQ * ND, (long)NSKV * ND, (long)NSQ * NSKV);
  // masked softmax -> P bf16
  softmax_mask<<<dim3(NB * NSQ), 256, 0, stream>>>(scoresf, mask, pb);
  // ctx = P @ V (NT vs Vt): z=4
  gemm256<0, 1><<<dim3(4, 8, 4), 512, SMEM, stream>>>(
      pb, vtb, nullptr, 0, 1.f, ctxb, NSKV, NSKV, 8192, ND,
      (long)NSQ * NSKV, (long)NSKV, (long)NSQ * ND);
  // out = ctx @ Wo^T + bo -> fp32
  gemm256<1, 0><<<dim3(4, 32, 1), 512, SMEM, stream>>>(
      ctxb, wob, bo, 0, 1.f, out, ND, ND, ND, ND, 0, 0, 0);
}

// Round 10
// 376.629 us; speedup vs baseline: 1.1692x; 1.0543x over previous
//
#include <hip/hip_runtime.h>
#include <hip/hip_bf16.h>
#include <math.h>

// Problem constants
#define NB 4
#define NSQ 2048
#define NSKV 2048
#define ND 1024

typedef __attribute__((ext_vector_type(8))) __bf16 bf16x8;
typedef __attribute__((ext_vector_type(4))) float f32x4;

#define WAITV(N) asm volatile("s_waitcnt vmcnt(" #N ")" ::: "memory")
#define WAITL0() asm volatile("s_waitcnt lgkmcnt(0)" ::: "memory")
#define BAR() __builtin_amdgcn_s_barrier()

__device__ __forceinline__ unsigned short f2bf(float x) {
  __hip_bfloat16 h = __float2bfloat16(x);
  return __builtin_bit_cast(unsigned short, h);
}

__device__ __forceinline__ void gload_lds16(const void* g, void* l) {
  __builtin_amdgcn_global_load_lds((const __attribute__((address_space(1))) void*)g,
                                   (__attribute__((address_space(3))) void*)l,
                                   16, 0, 0);
}

// ---------------- fp32 -> bf16 conversion (vectorized) ----------------
__global__ __launch_bounds__(256) void cvt_bf16(const float* __restrict__ s,
                                                unsigned short* __restrict__ d,
                                                int n4) {
  int i = blockIdx.x * blockDim.x + threadIdx.x;
  if (i >= n4) return;
  float4 v = ((const float4*)s)[i];
  ushort4 o;
  o.x = f2bf(v.x); o.y = f2bf(v.y); o.z = f2bf(v.z); o.w = f2bf(v.w);
  ((ushort4*)d)[i] = o;
}

__global__ __launch_bounds__(256) void concat_bias(const float* __restrict__ a,
                                                   const float* __restrict__ b,
                                                   float* __restrict__ d) {
  int i = blockIdx.x * 256 + threadIdx.x;
  if (i < 1024) d[i] = a[i];
  else if (i < 2048) d[i] = b[i - 1024];
}

// ---------------- 256x256 8-phase NT GEMM (verified round-5) ----------------
template <int BIAS_MODE, int OUT_BF16>   // BIAS: 0 none, 1 bias[col], 2 bias[row]
__global__ __launch_bounds__(512)
void gemm256(const unsigned short* __restrict__ A,
             const unsigned short* __restrict__ B,
             const float* __restrict__ bias, int biasStride, float scale,
             void* __restrict__ Cout,
             int K, int lda, int ldb, int ldc,
             long strideA, long strideB, long strideC) {
  extern __shared__ __align__(16) char smem[];
  char* ldsA = smem;            // [2][2][128][64] bf16
  char* ldsB = smem + 65536;

  const int tid = threadIdx.x;
  const int w  = tid >> 6;
  const int l  = tid & 63;
  const int wm = w >> 2;        // 0..1
  const int wn = w & 3;         // 0..3
  const int fr = l & 15;
  const int fq = l >> 4;

  const long brow = (long)blockIdx.y * 256;
  const long bcol = (long)blockIdx.x * 256;
  const unsigned short* Ab = A + (long)blockIdx.z * strideA;
  const unsigned short* Bb = B + (long)blockIdx.z * strideB;
  const float* biasb = (BIAS_MODE ? bias + (long)blockIdx.z * (long)biasStride : nullptr);

  const int NT = K >> 6;

  int srow[2], skc[2];
#pragma unroll
  for (int r = 0; r < 2; ++r) {
    int c = r * 512 + w * 64 + l;
    srow[r] = c >> 3;
    skc[r] = ((c & 7) - srow[r]) & 7;
  }
  const int sldsoff0 = (w * 64) * 16;
  const int sldsoff1 = (512 + w * 64) * 16;

  auto STAGE = [&](int isB, int T, int h) {
    const unsigned short* Gb = isB ? Bb : Ab;
    const int ld = isB ? ldb : lda;
    const long rb = (isB ? bcol : brow) + h * 128;
    char* seg = (isB ? ldsB : ldsA) + (T & 1) * 32768 + h * 16384;
    gload_lds16(Gb + (rb + srow[0]) * (long)ld + T * 64 + skc[0] * 8, seg + sldsoff0);
    gload_lds16(Gb + (rb + srow[1]) * (long)ld + T * 64 + skc[1] * 8, seg + sldsoff1);
  };

  auto LDFRAG = [&](const char* seg, int row, int kc) -> bf16x8 {
    return *(const bf16x8*)(seg + row * 128 + (((kc + row) & 7) << 4));
  };

  f32x4 acc[8][4];
#pragma unroll
  for (int mi = 0; mi < 8; ++mi)
#pragma unroll
    for (int ni = 0; ni < 4; ++ni) {
      f32x4 z = {0.f, 0.f, 0.f, 0.f};
      acc[mi][ni] = z;
    }

  bf16x8 af[4][2], bfr[2][2];

  STAGE(0, 0, 0); STAGE(1, 0, 0); STAGE(1, 0, 1); STAGE(0, 0, 1);
  WAITV(4);
  STAGE(0, 1, 0); STAGE(1, 1, 1); STAGE(0, 1, 1);
  WAITV(6);
  BAR();

  for (int t = 0; t < NT; ++t) {
    const int cb = t & 1;
    const char* a0 = ldsA + cb * 32768;
    const char* a1 = a0 + 16384;
    const char* b0 = ldsB + cb * 32768;
    const char* b1 = b0 + 16384;

    // ---- P1: read A-mlo + B-nlo ; stage (t+1).Bh0 ; mfma mlo x nlo
#pragma unroll
    for (int mi = 0; mi < 4; ++mi)
#pragma unroll
      for (int ks = 0; ks < 2; ++ks)
        af[mi][ks] = LDFRAG(a0, wm * 64 + mi * 16 + fr, ks * 4 + fq);
#pragma unroll
    for (int ni = 0; ni < 2; ++ni)
#pragma unroll
      for (int ks = 0; ks < 2; ++ks)
        bfr[ni][ks] = LDFRAG(b0, wn * 32 + ni * 16 + fr, ks * 4 + fq);
    if (t + 1 < NT) STAGE(1, t + 1, 0);
    BAR(); WAITL0();
    __builtin_amdgcn_s_setprio(1);
#pragma unroll
    for (int ks = 0; ks < 2; ++ks)
#pragma unroll
      for (int mi = 0; mi < 4; ++mi)
#pragma unroll
        for (int ni = 0; ni < 2; ++ni)
          acc[mi][ni] = __builtin_amdgcn_mfma_f32_16x16x32_bf16(af[mi][ks], bfr[ni][ks], acc[mi][ni], 0, 0, 0);
    __builtin_amdgcn_s_setprio(0);
    BAR();

    // ---- P2: read B-nhi ; stage (t+2).Ah0 ; mfma mlo x nhi
#pragma unroll
    for (int ni = 0; ni < 2; ++ni)
#pragma unroll
      for (int ks = 0; ks < 2; ++ks)
        bfr[ni][ks] = LDFRAG(b1, wn * 32 + ni * 16 + fr, ks * 4 + fq);
    if (t + 2 < NT) STAGE(0, t + 2, 0);
    BAR(); WAITL0();
    __builtin_amdgcn_s_setprio(1);
#pragma unroll
    for (int ks = 0; ks < 2; ++ks)
#pragma unroll
      for (int mi = 0; mi < 4; ++mi)
#pragma unroll
        for (int ni = 0; ni < 2; ++ni)
          acc[mi][2 + ni] = __builtin_amdgcn_mfma_f32_16x16x32_bf16(af[mi][ks], bfr[ni][ks], acc[mi][2 + ni], 0, 0, 0);
    __builtin_amdgcn_s_setprio(0);
    BAR();

    // ---- P3: read A-mhi ; stage (t+2).Bh1 ; mfma mhi x nhi
#pragma unroll
    for (int mi = 0; mi < 4; ++mi)
#pragma unroll
      for (int ks = 0; ks < 2; ++ks)
        af[mi][ks] = LDFRAG(a1, wm * 64 + mi * 16 + fr, ks * 4 + fq);
    if (t + 2 < NT) STAGE(1, t + 2, 1);
    BAR(); WAITL0();
    __builtin_amdgcn_s_setprio(1);
#pragma unroll
    for (int ks = 0; ks < 2; ++ks)
#pragma unroll
      for (int mi = 0; mi < 4; ++mi)
#pragma unroll
        for (int ni = 0; ni < 2; ++ni)
          acc[4 + mi][2 + ni] = __builtin_amdgcn_mfma_f32_16x16x32_bf16(af[mi][ks], bfr[ni][ks], acc[4 + mi][2 + ni], 0, 0, 0);
    __builtin_amdgcn_s_setprio(0);
    BAR();

    // ---- P4: re-read B-nlo ; stage (t+2).Ah1 ; mfma mhi x nlo ; group-end vmcnt
#pragma unroll
    for (int ni = 0; ni < 2; ++ni)
#pragma unroll
      for (int ks = 0; ks < 2; ++ks)
        bfr[ni][ks] = LDFRAG(b0, wn * 32 + ni * 16 + fr, ks * 4 + fq);
    if (t + 2 < NT) STAGE(0, t + 2, 1);
    BAR(); WAITL0();
    __builtin_amdgcn_s_setprio(1);
#pragma unroll
    for (int ks = 0; ks < 2; ++ks)
#pragma unroll
      for (int mi = 0; mi < 4; ++mi)
#pragma unroll
        for (int ni = 0; ni < 2; ++ni)
          acc[4 + mi][ni] = __builtin_amdgcn_mfma_f32_16x16x32_bf16(af[mi][ks], bfr[ni][ks], acc[4 + mi][ni], 0, 0, 0);
    __builtin_amdgcn_s_setprio(0);
    if (t < NT - 2) { WAITV(6); } else if (t == NT - 2) { WAITV(0); }
    BAR();
  }

#pragma unroll
  for (int mi = 0; mi < 8; ++mi) {
#pragma unroll
    for (int ni = 0; ni < 4; ++ni) {
#pragma unroll
      for (int r = 0; r < 4; ++r) {
        long row = brow + (mi >> 2) * 128 + wm * 64 + (mi & 3) * 16 + fq * 4 + r;
        long col = bcol + (ni >> 1) * 128 + wn * 32 + (ni & 1) * 16 + fr;
        float v = acc[mi][ni][r] * scale;
        if (BIAS_MODE == 1) v += biasb[col];
        if (BIAS_MODE == 2) v += biasb[row];
        long idx = (long)blockIdx.z * strideC + row * (long)ldc + col;
        if (OUT_BF16)
          ((unsigned short*)Cout)[idx] = f2bf(v);
        else
          ((float*)Cout)[idx] = v;
      }
    }
  }
}

// ---------------- 256x128 2-phase NT GEMM (for N<=1024 shapes: full 256-block grids) ----
// BM=256, BN=128, BK=64, 512 threads = 8 waves (2M x 4N), per-wave out 128x32.
// LDS: A[2buf][2half][128][64] (64KB) + B[2buf][128][64] (32KB) = 96KB.
// Schedule: P1{read b+a0; stage (t+1).Ah1; mfma mlo} P2{read a1; stage (t+2).{B,Ah0}; mfma mhi}
// vmcnt: WAITV(6) at P1-end (retires Ah1(t)) and iter-end (retires (t+1).{B,Ah0}).
template <int BIAS_MODE, int OUT_BF16>
__global__ __launch_bounds__(512)
void gemm128n(const unsigned short* __restrict__ A,
              const unsigned short* __restrict__ B,
              const float* __restrict__ bias, int biasStride, float scale,
              void* __restrict__ Cout,
              int K, int lda, int ldb, int ldc,
              long strideA, long strideB, long strideC) {
  extern __shared__ __align__(16) char smem[];
  char* ldsA = smem;            // [2][2][128][64] bf16 = 64KB
  char* ldsB = smem + 65536;    // [2][128][64] bf16 = 32KB

  const int tid = threadIdx.x;
  const int w  = tid >> 6;
  const int l  = tid & 63;
  const int wm = w >> 2;        // 0..1
  const int wn = w & 3;         // 0..3
  const int fr = l & 15;
  const int fq = l >> 4;

  const long brow = (long)blockIdx.y * 256;
  const long bcol = (long)blockIdx.x * 128;
  const unsigned short* Ab = A + (long)blockIdx.z * strideA;
  const unsigned short* Bb = B + (long)blockIdx.z * strideB;
  const float* biasb = (BIAS_MODE ? bias + (long)blockIdx.z * (long)biasStride : nullptr);

  const int NT = K >> 6;

  int srow[2], skc[2];
#pragma unroll
  for (int r = 0; r < 2; ++r) {
    int c = r * 512 + w * 64 + l;
    srow[r] = c >> 3;
    skc[r] = ((c & 7) - srow[r]) & 7;
  }
  const int sldsoff0 = (w * 64) * 16;
  const int sldsoff1 = (512 + w * 64) * 16;

  auto STAGEA = [&](int T, int h) {
    char* seg = ldsA + (T & 1) * 32768 + h * 16384;
    gload_lds16(Ab + (brow + h * 128 + srow[0]) * (long)lda + T * 64 + skc[0] * 8, seg + sldsoff0);
    gload_lds16(Ab + (brow + h * 128 + srow[1]) * (long)lda + T * 64 + skc[1] * 8, seg + sldsoff1);
  };
  auto STAGEB = [&](int T) {
    char* seg = ldsB + (T & 1) * 16384;
    gload_lds16(Bb + (bcol + srow[0]) * (long)ldb + T * 64 + skc[0] * 8, seg + sldsoff0);
    gload_lds16(Bb + (bcol + srow[1]) * (long)ldb + T * 64 + skc[1] * 8, seg + sldsoff1);
  };
  auto LDFRAG = [&](const char* seg, int row, int kc) -> bf16x8 {
    return *(const bf16x8*)(seg + row * 128 + (((kc + row) & 7) << 4));
  };

  f32x4 acc[8][2];
#pragma unroll
  for (int mi = 0; mi < 8; ++mi)
#pragma unroll
    for (int ni = 0; ni < 2; ++ni) {
      f32x4 z = {0.f, 0.f, 0.f, 0.f};
      acc[mi][ni] = z;
    }

  bf16x8 af[4][2], bfr[2][2];

  // prologue: tile0 fully {B,Ah0,Ah1}; tile1 {B,Ah0} (Ah1(1) staged in iter0-P1)
  STAGEB(0); STAGEA(0, 0); STAGEA(0, 1);
  STAGEB(1); STAGEA(1, 0);
  WAITV(4);   // tile0 landed
  BAR();

  for (int t = 0; t < NT; ++t) {
    const int cb = t & 1;
    const char* a0 = ldsA + cb * 32768;
    const char* a1 = a0 + 16384;
    const char* bb = ldsB + cb * 16384;

    // ---- P1: read b + a0 ; stage (t+1).Ah1 ; mfma mlo x n
#pragma unroll
    for (int ni = 0; ni < 2; ++ni)
#pragma unroll
      for (int ks = 0; ks < 2; ++ks)
        bfr[ni][ks] = LDFRAG(bb, wn * 32 + ni * 16 + fr, ks * 4 + fq);
#pragma unroll
    for (int mi = 0; mi < 4; ++mi)
#pragma unroll
      for (int ks = 0; ks < 2; ++ks)
        af[mi][ks] = LDFRAG(a0, wm * 64 + mi * 16 + fr, ks * 4 + fq);
    if (t + 1 < NT) STAGEA(t + 1, 1);
    BAR(); WAITL0();
    __builtin_amdgcn_s_setprio(1);
#pragma unroll
    for (int ks = 0; ks < 2; ++ks)
#pragma unroll
      for (int mi = 0; mi < 4; ++mi)
#pragma unroll
        for (int ni = 0; ni < 2; ++ni)
          acc[mi][ni] = __builtin_amdgcn_mfma_f32_16x16x32_bf16(af[mi][ks], bfr[ni][ks], acc[mi][ni], 0, 0, 0);
    __builtin_amdgcn_s_setprio(0);
    WAITV(6);   // retires Ah1(t) (oldest) before P2 reads it
    BAR();

    // ---- P2: read a1 ; stage (t+2).{B, Ah0} ; mfma mhi x n
#pragma unroll
    for (int mi = 0; mi < 4; ++mi)
#pragma unroll
      for (int ks = 0; ks < 2; ++ks)
        af[mi][ks] = LDFRAG(a1, wm * 64 + mi * 16 + fr, ks * 4 + fq);
    if (t + 2 < NT) { STAGEB(t + 2); STAGEA(t + 2, 0); }
    BAR(); WAITL0();
    __builtin_amdgcn_s_setprio(1);
#pragma unroll
    for (int ks = 0; ks < 2; ++ks)
#pragma unroll
      for (int mi = 0; mi < 4; ++mi)
#pragma unroll
        for (int ni = 0; ni < 2; ++ni)
          acc[4 + mi][ni] = __builtin_amdgcn_mfma_f32_16x16x32_bf16(af[mi][ks], bfr[ni][ks], acc[4 + mi][ni], 0, 0, 0);
    __builtin_amdgcn_s_setprio(0);
    if (t < NT - 2) { WAITV(6); } else if (t == NT - 2) { WAITV(0); }
    BAR();
  }

  // epilogue: C/D layout col=lane&15, row=(lane>>4)*4+reg
#pragma unroll
  for (int mi = 0; mi < 8; ++mi) {
#pragma unroll
    for (int ni = 0; ni < 2; ++ni) {
#pragma unroll
      for (int r = 0; r < 4; ++r) {
        long row = brow + (mi >> 2) * 128 + wm * 64 + (mi & 3) * 16 + fq * 4 + r;
        long col = bcol + wn * 32 + ni * 16 + fr;
        float v = acc[mi][ni][r] * scale;
        if (BIAS_MODE == 1) v += biasb[col];
        if (BIAS_MODE == 2) v += biasb[row];
        long idx = (long)blockIdx.z * strideC + row * (long)ldc + col;
        if (OUT_BF16)
          ((unsigned short*)Cout)[idx] = f2bf(v);
        else
          ((float*)Cout)[idx] = v;
      }
    }
  }
}

// ---------------- masked softmax over rows of 2048, fp32 -> bf16 ----------------
__global__ __launch_bounds__(256)
void softmax_mask(const float* __restrict__ S, const int* __restrict__ Mk,
                  unsigned short* __restrict__ P) {
  const long row = blockIdx.x;
  const float* s = S + row * NSKV;
  const int* mk = Mk + row * NSKV;
  unsigned short* p = P + row * NSKV;
  const int t = threadIdx.x;
  const int lane = t & 63;
  const int wave = t >> 6;

  float4 v0 = ((const float4*)s)[t * 2];
  float4 v1 = ((const float4*)s)[t * 2 + 1];
  int4 m0 = ((const int4*)mk)[t * 2];
  int4 m1 = ((const int4*)mk)[t * 2 + 1];
  float x[8];
  x[0] = m0.x ? v0.x : -1e10f;
  x[1] = m0.y ? v0.y : -1e10f;
  x[2] = m0.z ? v0.z : -1e10f;
  x[3] = m0.w ? v0.w : -1e10f;
  x[4] = m1.x ? v1.x : -1e10f;
  x[5] = m1.y ? v1.y : -1e10f;
  x[6] = m1.z ? v1.z : -1e10f;
  x[7] = m1.w ? v1.w : -1e10f;

  float mx = x[0];
#pragma unroll
  for (int j = 1; j < 8; ++j) mx = fmaxf(mx, x[j]);
#pragma unroll
  for (int o = 32; o > 0; o >>= 1) mx = fmaxf(mx, __shfl_xor(mx, o, 64));
  __shared__ float red[8];
  if (lane == 0) red[wave] = mx;
  __syncthreads();
  mx = fmaxf(fmaxf(red[0], red[1]), fmaxf(red[2], red[3]));

  float e[8];
  float sum = 0.f;
#pragma unroll
  for (int j = 0; j < 8; ++j) {
    e[j] = __expf(x[j] - mx);
    sum += e[j];
  }
#pragma unroll
  for (int o = 32; o > 0; o >>= 1) sum += __shfl_xor(sum, o, 64);
  if (lane == 0) red[4 + wave] = sum;
  __syncthreads();
  sum = red[4] + red[5] + red[6] + red[7];
  float inv = 1.f / sum;

  ushort4 o0, o1;
  o0.x = f2bf(e[0] * inv); o0.y = f2bf(e[1] * inv);
  o0.z = f2bf(e[2] * inv); o0.w = f2bf(e[3] * inv);
  o1.x = f2bf(e[4] * inv); o1.y = f2bf(e[5] * inv);
  o1.z = f2bf(e[6] * inv); o1.w = f2bf(e[7] * inv);
  ((ushort4*)p)[t * 2] = o0;
  ((ushort4*)p)[t * 2 + 1] = o1;
}

// ---------------- launcher ----------------
extern "C" void kernel_launch(void* const* d_in, const int* in_sizes, int n_in,
                              void* d_out, int out_size, void* d_ws, size_t ws_size,
                              hipStream_t stream) {
  const float* input  = (const float*)d_in[0];
  const float* memory = (const float*)d_in[1];
  const int*   mask   = (const int*)d_in[2];
  const float* Wq = (const float*)d_in[3];
  const float* bq = (const float*)d_in[4];
  const float* Wk = (const float*)d_in[5];
  const float* bk = (const float*)d_in[6];
  const float* Wv = (const float*)d_in[7];
  const float* bv = (const float*)d_in[8];
  const float* Wo = (const float*)d_in[9];
  const float* bo = (const float*)d_in[10];
  float* out = (float*)d_out;

  // workspace layout (ushort elements)
  unsigned short* wqb  = (unsigned short*)d_ws;
  unsigned short* wkb  = wqb + (1 << 20);
  unsigned short* wvb  = wkb + (1 << 20);
  unsigned short* wob  = wvb + (1 << 20);
  unsigned short* inb  = wob + (1 << 20);   // 8M elems
  unsigned short* memb = inb + (8 << 20);
  unsigned short* qb   = memb + (8 << 20);
  unsigned short* kb   = qb + (8 << 20);
  unsigned short* vtb  = kb + (8 << 20);    // Vt_all: [1024][8192]
  unsigned short* ctxb = vtb + (8 << 20);
  float* scoresf = (float*)(ctxb + (8 << 20));   // 16M floats
  float* biasqk  = scoresf + (16 << 20);         // 2048 floats
  unsigned short* pb = inb;  // P overlays inb+memb (16M ushorts), dead by then

  const int SMEM256 = 131072;
  const int SMEM128 = 98304;
  hipFuncSetAttribute((const void*)&gemm256<1, 1>, hipFuncAttributeMaxDynamicSharedMemorySize, SMEM256);
  hipFuncSetAttribute((const void*)&gemm256<0, 0>, hipFuncAttributeMaxDynamicSharedMemorySize, SMEM256);
  hipFuncSetAttribute((const void*)&gemm128n<2, 1>, hipFuncAttributeMaxDynamicSharedMemorySize, SMEM128);
  hipFuncSetAttribute((const void*)&gemm128n<0, 1>, hipFuncAttributeMaxDynamicSharedMemorySize, SMEM128);
  hipFuncSetAttribute((const void*)&gemm128n<1, 0>, hipFuncAttributeMaxDynamicSharedMemorySize, SMEM128);

  // conversions + bias concat
  cvt_bf16<<<dim3(8192), 256, 0, stream>>>(input, inb, 2097152);
  cvt_bf16<<<dim3(8192), 256, 0, stream>>>(memory, memb, 2097152);
  cvt_bf16<<<dim3(1024), 256, 0, stream>>>(Wq, wqb, 262144);
  cvt_bf16<<<dim3(1024), 256, 0, stream>>>(Wk, wkb, 262144);
  cvt_bf16<<<dim3(1024), 256, 0, stream>>>(Wv, wvb, 262144);
  cvt_bf16<<<dim3(1024), 256, 0, stream>>>(Wo, wob, 262144);
  concat_bias<<<dim3(8), 256, 0, stream>>>(bq, bk, biasqk);

  // fused Q/K projection: z=0 -> Q from input/Wq, z=1 -> K from memory/Wk (256 blocks)
  gemm256<1, 1><<<dim3(4, 32, 2), 512, SMEM256, stream>>>(
      inb, wqb, biasqk, 1024, 1.f, qb, ND, ND, ND, ND,
      (long)(8 << 20), (long)(1 << 20), (long)(8 << 20));
  // Vt = Wv @ memory^T + bv(row): [1024][8192]  (4y x 64x = 256 blocks)
  gemm128n<2, 1><<<dim3(64, 4, 1), 512, SMEM128, stream>>>(
      wvb, memb, bv, 0, 1.f, vtb, ND, ND, ND, 8192, 0, 0, 0);
  // scores = (Q K^T) * 1/32 -> fp32, z=4 (256 blocks)
  gemm256<0, 0><<<dim3(8, 8, 4), 512, SMEM256, stream>>>(
      qb, kb, nullptr, 0, 0.03125f, scoresf, ND, ND, ND, NSKV,
      (long)NSQ * ND, (long)NSKV * ND, (long)NSQ * NSKV);
  // masked softmax -> P bf16
  softmax_mask<<<dim3(NB * NSQ), 256, 0, stream>>>(scoresf, mask, pb);
  // ctx = P @ V (NT vs Vt): 8x x 8y x 4z = 256 blocks
  gemm128n<0, 1><<<dim3(8, 8, 4), 512, SMEM128, stream>>>(
      pb, vtb, nullptr, 0, 1.f, ctxb, NSKV, NSKV, 8192, ND,
      (long)NSQ * NSKV, (long)NSKV, (long)NSQ * ND);
  // out = ctx @ Wo^T + bo -> fp32 (8x x 32y = 256 blocks)
  gemm128n<1, 0><<<dim3(8, 32, 1), 512, SMEM128, stream>>>(
      ctxb, wob, bo, 0, 1.f, out, ND, ND, ND, ND, 0, 0, 0);
}